// Round 5
// baseline (3359.028 us; speedup 1.0000x reference)
//
#include <hip/hip_runtime.h>
#include <math.h>
#include <limits.h>

#define DIM 2048
#define NEXP 256
#define TOPK 8
#define BM 16
#define BK 16
#define NTH 256
#define NTILE (DIM / BK)   // 128 k-tiles

// np-einsum fp32 replica (LOCKED by R3 pass — do not perturb):
//   4 partial chains per output, chain j takes k ≡ j (mod 4);
//   k in 16-groups ascending, within group chunk order 3,2,1,0;
//   separate mul/add rounding (no fma); hadd tree (l0+l1)+(l2+l3);
//   sigmoid in f64 -> f32; pairwise-8 weight sum; ties -> lower index.
// BK=16 == one 16-group per tile; chain order identical to R3/R4.

__device__ __forceinline__ void gload16(const void* gptr, void* lptr) {
    __builtin_amdgcn_global_load_lds(
        (const __attribute__((address_space(1))) unsigned int*)(unsigned long long)gptr,
        (__attribute__((address_space(3))) unsigned int*)(unsigned int)(unsigned long long)lptr,
        16, 0, 0);
}

__global__ __launch_bounds__(NTH, 4) void gate_kernel(
    const float* __restrict__ x, const float* __restrict__ w,
    const float* __restrict__ bias, float* __restrict__ outw,
    float* __restrict__ outi)
{
#pragma clang fp contract(off)
    // wbuf[buf] layout: float index (c*256 + e)*4 + j   (chunk c=0..3, expert e, j=k%4)
    __shared__ float wbuf[2][4 * NEXP * 4];   // 32 KB
    __shared__ float xbuf[2][BM * BK];        // 2 KB  [row*16 + k]

    const int tid  = threadIdx.x;
    const int tidx = tid & 31;               // expert lane: experts tidx + 32*m
    const int r0   = (tid >> 5) * 2;         // 2 rows per thread
    const int gr   = blockIdx.x * BM;

    const char* wbytes = (const char*)w;
    const char* xbytes = (const char*)x;
    // per-thread invariant bases
    const char* wbase = wbytes + (size_t)tid * (DIM * 4);   // expert row `tid`
    const int xrow = tid >> 2, xq = tid & 3;                // tid<64 stages x
    const char* xbase = xbytes + ((size_t)(gr + xrow) * DIM + xq * 4) * 4;

    auto stage = [&](int buf, int kt) {
        const size_t kb = (size_t)kt * 64;   // 16 floats per tile = 64 B
#pragma unroll
        for (int c = 0; c < 4; ++c)
            gload16(wbase + kb + c * 16, (char*)&wbuf[buf][0] + c * 4096 + tid * 16);
        if (tid < 64)
            gload16(xbase + kb, (char*)&xbuf[buf][0] + tid * 16);
    };

    float acc[2][8][4];
#pragma unroll
    for (int r = 0; r < 2; ++r)
#pragma unroll
        for (int m = 0; m < 8; ++m)
#pragma unroll
            for (int j = 0; j < 4; ++j) acc[r][m][j] = 0.0f;

    auto compute = [&](int buf) {
#pragma clang fp contract(off)
#pragma unroll
        for (int i = 3; i >= 0; --i) {          // reversed chunk order in 16-group
            const int c = i;
            const float4 x0 = *(const float4*)&xbuf[buf][r0 * BK + c * 4];
            const float4 x1 = *(const float4*)&xbuf[buf][(r0 + 1) * BK + c * 4];
            const float* wb = &wbuf[buf][(c * 256 + tidx) * 4];
#pragma unroll
            for (int m = 0; m < 8; ++m) {
                const float4 wv = *(const float4*)(wb + m * 128);
                acc[0][m][0] = acc[0][m][0] + x0.x * wv.x;
                acc[0][m][1] = acc[0][m][1] + x0.y * wv.y;
                acc[0][m][2] = acc[0][m][2] + x0.z * wv.z;
                acc[0][m][3] = acc[0][m][3] + x0.w * wv.w;
                acc[1][m][0] = acc[1][m][0] + x1.x * wv.x;
                acc[1][m][1] = acc[1][m][1] + x1.y * wv.y;
                acc[1][m][2] = acc[1][m][2] + x1.z * wv.z;
                acc[1][m][3] = acc[1][m][3] + x1.w * wv.w;
            }
        }
    };

    // ---- main loop: double-buffered global_load_lds pipeline ----
    stage(0, 0);
    __syncthreads();
    for (int kt = 0; kt < NTILE; ++kt) {
        const int buf = kt & 1;
        if (kt + 1 < NTILE) stage(buf ^ 1, kt + 1);
        compute(buf);
        __syncthreads();
    }

    // ---- epilogue: hadd tree + f64 sigmoid -> scores in wbuf[0] ----
    float* sc = &wbuf[0][0];                 // [16][256] = 16 KB (exact fit)
#pragma unroll
    for (int r = 0; r < 2; ++r)
#pragma unroll
        for (int m = 0; m < 8; ++m) {
            const float l01 = acc[r][m][0] + acc[r][m][1];
            const float l23 = acc[r][m][2] + acc[r][m][3];
            const float logit = l01 + l23;
            const double s = 1.0 / (1.0 + exp(-(double)logit));
            sc[(r0 + r) * NEXP + (tidx + 32 * m)] = (float)s;
        }
    __syncthreads();

    float* cval = &wbuf[1][0];               // [16][64]
    int*   cidx = (int*)&wbuf[1][1024];      // [16][64]

    // ---- per-row top-8: 8 subs/row on first 128 threads ----
    if (tid < 128) {
        const int row = tid >> 3;
        const int sub = tid & 7;
        float tv[TOPK];
        int   ti[TOPK];
#pragma unroll
        for (int q = 0; q < TOPK; ++q) { tv[q] = -INFINITY; ti[q] = INT_MAX; }
        for (int j = 0; j < 32; ++j) {
            const int e = sub + (j << 3);    // ascending index => stable
            const float v = sc[row * NEXP + e] + bias[e];
            if (v > tv[TOPK - 1]) {
                int p = TOPK - 1;
                while (p > 0 && v > tv[p - 1]) {
                    tv[p] = tv[p - 1]; ti[p] = ti[p - 1]; --p;
                }
                tv[p] = v; ti[p] = e;
            }
        }
#pragma unroll
        for (int q = 0; q < TOPK; ++q) {
            cval[row * 64 + sub * 8 + q] = tv[q];
            cidx[row * 64 + sub * 8 + q] = ti[q];
        }
    }
    __syncthreads();

    // ---- leaders merge 8 sorted lists; ties -> lower index; output ----
    if (tid < 128 && (tid & 7) == 0) {
        const int row = tid >> 3;
        int p[8];
#pragma unroll
        for (int s = 0; s < 8; ++s) p[s] = 0;
        float g[TOPK];
        int   sel[TOPK];
        for (int k = 0; k < TOPK; ++k) {
            float best = -INFINITY;
            int bidx = INT_MAX;
            int bs = 0;
            for (int s = 0; s < 8; ++s) {
                if (p[s] < 8) {
                    const float v = cval[row * 64 + s * 8 + p[s]];
                    const int  id = cidx[row * 64 + s * 8 + p[s]];
                    if (v > best || (v == best && id < bidx)) {
                        best = v; bidx = id; bs = s;
                    }
                }
            }
            p[bs]++;
            sel[k] = bidx;
            g[k] = sc[row * NEXP + bidx];    // original score (no bias)
        }
        const float s01 = g[0] + g[1], s23 = g[2] + g[3];
        const float s45 = g[4] + g[5], s67 = g[6] + g[7];
        const float wsum = (s01 + s23) + (s45 + s67);
        const float den = wsum + 1e-20f;
        const size_t orow = (size_t)(gr + row) * TOPK;
#pragma unroll
        for (int k = 0; k < TOPK; ++k) {
            outw[orow + k] = (g[k] / den) * 2.5f;
            outi[orow + k] = (float)sel[k];
        }
    }
}

extern "C" void kernel_launch(void* const* d_in, const int* in_sizes, int n_in,
                              void* d_out, int out_size, void* d_ws, size_t ws_size,
                              hipStream_t stream) {
    const float* x    = (const float*)d_in[0];
    const float* w    = (const float*)d_in[1];
    const float* bias = (const float*)d_in[2];
    float* outw = (float*)d_out;
    const int M = in_sizes[0] / DIM;              // 16384 rows
    float* outi = outw + (size_t)M * TOPK;
    const int grid = M / BM;                      // 1024 blocks
    hipLaunchKernelGGL(gate_kernel, dim3(grid), dim3(NTH), 0, stream,
                       x, w, bias, outw, outi);
}

// Round 6
// 516.853 us; speedup vs baseline: 6.4990x; 6.4990x over previous
//
#include <hip/hip_runtime.h>
#include <math.h>
#include <limits.h>

#define DIM 2048
#define NEXP 256
#define TOPK 8
#define BM 16
#define BK 16
#define NTH 256
#define NTILE (DIM / BK)   // 128 k-tiles

// np-einsum fp32 replica (LOCKED by R3/R4/R5 passes — do not perturb):
//   4 partial chains per output, chain j takes k ≡ j (mod 4);
//   k in 16-groups ascending, within group chunk order 3,2,1,0;
//   separate mul/add rounding (no fma); hadd tree (l0+l1)+(l2+l3);
//   sigmoid in f64 -> f32; pairwise-8 weight sum; ties -> lower index.
// Thread tile 4 rows x 4 experts: w ds_read amortized over 4 rows
// (LDS-read-bound fix); x reads are wave-uniform broadcasts.

__device__ __forceinline__ void gload16(const void* gptr, void* lptr) {
    __builtin_amdgcn_global_load_lds(
        (const __attribute__((address_space(1))) unsigned int*)(unsigned long long)gptr,
        (__attribute__((address_space(3))) unsigned int*)(unsigned int)(unsigned long long)lptr,
        16, 0, 0);
}

__global__ __launch_bounds__(NTH) void gate_kernel(
    const float* __restrict__ x, const float* __restrict__ w,
    const float* __restrict__ bias, float* __restrict__ outw,
    float* __restrict__ outi)
{
#pragma clang fp contract(off)
    // wbuf[buf] layout: float index (c*256 + e)*4 + j  (chunk c=0..3, expert e, j=k%4)
    __shared__ float wbuf[2][4 * NEXP * 4];   // 32 KB
    __shared__ float xbuf[2][BM * BK];        // 2 KB  [row*16 + k]

    const int tid  = threadIdx.x;
    const int tidx = tid & 63;               // expert lane: experts tidx + 64*i
    const int r0   = (tid >> 6) * 4;         // 4 rows per thread
    const int gr   = blockIdx.x * BM;

    const char* wbase = (const char*)w + (size_t)tid * (DIM * 4);   // expert row `tid`
    const int xrow = tid >> 2, xq = tid & 3;                        // tid<64 stages x
    const char* xbase = (const char*)x + ((size_t)(gr + xrow) * DIM + xq * 4) * 4;

    auto stage = [&](int buf, int kt) {
        const size_t kb = (size_t)kt * 64;   // 16 floats per tile = 64 B
#pragma unroll
        for (int c = 0; c < 4; ++c)
            gload16(wbase + kb + c * 16, (char*)&wbuf[buf][0] + c * 4096 + tid * 16);
        if (tid < 64)
            gload16(xbase + kb, (char*)&xbuf[buf][0] + tid * 16);
    };

    float acc[4][4][4];                      // [row r][expert i][chain j]
#pragma unroll
    for (int r = 0; r < 4; ++r)
#pragma unroll
        for (int i = 0; i < 4; ++i)
#pragma unroll
            for (int j = 0; j < 4; ++j) acc[r][i][j] = 0.0f;

    auto compute = [&](int buf) {
#pragma clang fp contract(off)
#pragma unroll
        for (int c = 3; c >= 0; --c) {          // reversed chunk order in 16-group
            float4 xv[4];
#pragma unroll
            for (int r = 0; r < 4; ++r)
                xv[r] = *(const float4*)&xbuf[buf][(r0 + r) * BK + c * 4];  // broadcast
#pragma unroll
            for (int i = 0; i < 4; ++i) {
                const float4 wv = *(const float4*)&wbuf[buf][(c * 256 + tidx + 64 * i) * 4];
#pragma unroll
                for (int r = 0; r < 4; ++r) {
                    acc[r][i][0] = acc[r][i][0] + xv[r].x * wv.x;
                    acc[r][i][1] = acc[r][i][1] + xv[r].y * wv.y;
                    acc[r][i][2] = acc[r][i][2] + xv[r].z * wv.z;
                    acc[r][i][3] = acc[r][i][3] + xv[r].w * wv.w;
                }
            }
        }
    };

    // ---- main loop: double-buffered global_load_lds pipeline ----
    stage(0, 0);
    __syncthreads();
    for (int kt = 0; kt < NTILE; ++kt) {
        const int buf = kt & 1;
        if (kt + 1 < NTILE) stage(buf ^ 1, kt + 1);
        compute(buf);
        __syncthreads();
    }

    // ---- epilogue: hadd tree + f64 sigmoid -> scores in wbuf[0] ----
    float* sc = &wbuf[0][0];                 // [16][256] = 16 KB (exact fit)
#pragma unroll
    for (int r = 0; r < 4; ++r)
#pragma unroll
        for (int i = 0; i < 4; ++i) {
            const float l01 = acc[r][i][0] + acc[r][i][1];
            const float l23 = acc[r][i][2] + acc[r][i][3];
            const float logit = l01 + l23;
            const double s = 1.0 / (1.0 + exp(-(double)logit));
            sc[(r0 + r) * NEXP + (tidx + 64 * i)] = (float)s;
        }
    __syncthreads();

    float* cval = &wbuf[1][0];               // [16][64]
    int*   cidx = (int*)&wbuf[1][1024];      // [16][64]

    // ---- per-row top-8: 8 subs/row on first 128 threads ----
    if (tid < 128) {
        const int row = tid >> 3;
        const int sub = tid & 7;
        float tv[TOPK];
        int   ti[TOPK];
#pragma unroll
        for (int q = 0; q < TOPK; ++q) { tv[q] = -INFINITY; ti[q] = INT_MAX; }
        for (int j = 0; j < 32; ++j) {
            const int e = sub + (j << 3);    // ascending index => stable
            const float v = sc[row * NEXP + e] + bias[e];
            if (v > tv[TOPK - 1]) {
                int p = TOPK - 1;
                while (p > 0 && v > tv[p - 1]) {
                    tv[p] = tv[p - 1]; ti[p] = ti[p - 1]; --p;
                }
                tv[p] = v; ti[p] = e;
            }
        }
#pragma unroll
        for (int q = 0; q < TOPK; ++q) {
            cval[row * 64 + sub * 8 + q] = tv[q];
            cidx[row * 64 + sub * 8 + q] = ti[q];
        }
    }
    __syncthreads();

    // ---- leaders merge 8 sorted lists; ties -> lower index; output ----
    if (tid < 128 && (tid & 7) == 0) {
        const int row = tid >> 3;
        int p[8];
#pragma unroll
        for (int s = 0; s < 8; ++s) p[s] = 0;
        float g[TOPK];
        int   sel[TOPK];
        for (int k = 0; k < TOPK; ++k) {
            float best = -INFINITY;
            int bidx = INT_MAX;
            int bs = 0;
            for (int s = 0; s < 8; ++s) {
                if (p[s] < 8) {
                    const float v = cval[row * 64 + s * 8 + p[s]];
                    const int  id = cidx[row * 64 + s * 8 + p[s]];
                    if (v > best || (v == best && id < bidx)) {
                        best = v; bidx = id; bs = s;
                    }
                }
            }
            p[bs]++;
            sel[k] = bidx;
            g[k] = sc[row * NEXP + bidx];    // original score (no bias)
        }
        const float s01 = g[0] + g[1], s23 = g[2] + g[3];
        const float s45 = g[4] + g[5], s67 = g[6] + g[7];
        const float wsum = (s01 + s23) + (s45 + s67);
        const float den = wsum + 1e-20f;
        const size_t orow = (size_t)(gr + row) * TOPK;
#pragma unroll
        for (int k = 0; k < TOPK; ++k) {
            outw[orow + k] = (g[k] / den) * 2.5f;
            outi[orow + k] = (float)sel[k];
        }
    }
}

extern "C" void kernel_launch(void* const* d_in, const int* in_sizes, int n_in,
                              void* d_out, int out_size, void* d_ws, size_t ws_size,
                              hipStream_t stream) {
    const float* x    = (const float*)d_in[0];
    const float* w    = (const float*)d_in[1];
    const float* bias = (const float*)d_in[2];
    float* outw = (float*)d_out;
    const int M = in_sizes[0] / DIM;              // 16384 rows
    float* outi = outw + (size_t)M * TOPK;
    const int grid = M / BM;                      // 1024 blocks
    hipLaunchKernelGGL(gate_kernel, dim3(grid), dim3(NTH), 0, stream,
                       x, w, bias, outw, outi);
}